// Round 5
// baseline (247.466 us; speedup 1.0000x reference)
//
#include <hip/hip_runtime.h>
#include <math.h>

// B=64 rows, T=524288 cols, f32. loss = mean_i ||pred_i - true_i||_2.
// R5: nt loads (keep L3 restore-resident lines intact) + larger contiguous
// span per block (128 KB/input) for DRAM page locality; grid=1024 = one
// residency wave, no dispatch tail.

#define B_ROWS 64
#define T_ELEMS 524288
#define CHUNKS_PER_ROW 16           // 1024 blocks total
#define BLOCK 256
#define BATCHES 4                   // 4 x 8 f4 per input per thread

typedef float f4 __attribute__((ext_vector_type(4)));

// T/4 = 131072 f4/row/input; per chunk 8192 f4 (128 KB); per thread 32 f4.

__global__ __launch_bounds__(BLOCK) void sdtw_stage1(
    const f4* __restrict__ yp, const f4* __restrict__ yt,
    float* __restrict__ partial)
{
    const int row   = blockIdx.x >> 4;          // / CHUNKS_PER_ROW
    const int chunk = blockIdx.x & (CHUNKS_PER_ROW - 1);
    const int T4        = T_ELEMS / 4;          // 131072
    const int per_chunk = T4 / CHUNKS_PER_ROW;  // 8192 f4
    const size_t base = (size_t)row * T4 + (size_t)chunk * per_chunk;

    float acc0 = 0.0f, acc1 = 0.0f;
#pragma unroll
    for (int b = 0; b < BATCHES; ++b) {
        const size_t idx = base + (size_t)b * (8 * BLOCK) + threadIdx.x;
        f4 A[8], Bv[8];
#pragma unroll
        for (int i = 0; i < 8; ++i)
            A[i]  = __builtin_nontemporal_load(&yp[idx + (size_t)i * BLOCK]);
#pragma unroll
        for (int i = 0; i < 8; ++i)
            Bv[i] = __builtin_nontemporal_load(&yt[idx + (size_t)i * BLOCK]);
#pragma unroll
        for (int i = 0; i < 8; ++i) {
            f4 d = A[i] - Bv[i];
            float p = d.x * d.x + d.y * d.y + d.z * d.z + d.w * d.w;
            if (i & 1) acc1 += p; else acc0 += p;
        }
    }
    float acc = acc0 + acc1;

    // wave-64 shuffle reduction
    for (int off = 32; off > 0; off >>= 1)
        acc += __shfl_down(acc, off, 64);

    __shared__ float s[BLOCK / 64];
    const int lane = threadIdx.x & 63;
    const int wave = threadIdx.x >> 6;
    if (lane == 0) s[wave] = acc;
    __syncthreads();
    if (threadIdx.x == 0) {
        float r = 0.0f;
#pragma unroll
        for (int w = 0; w < BLOCK / 64; ++w) r += s[w];
        partial[blockIdx.x] = r;   // layout: row*CHUNKS_PER_ROW + chunk
    }
}

__global__ __launch_bounds__(64) void sdtw_stage2(
    const float* __restrict__ partial, float* __restrict__ out)
{
    // one wave: thread i handles row i
    float acc = 0.0f;
#pragma unroll
    for (int k = 0; k < CHUNKS_PER_ROW; ++k)
        acc += partial[threadIdx.x * CHUNKS_PER_ROW + k];
    float norm = sqrtf(acc);
    for (int off = 32; off > 0; off >>= 1)
        norm += __shfl_down(norm, off, 64);
    if (threadIdx.x == 0)
        out[0] = norm * (1.0f / (float)B_ROWS);
}

extern "C" void kernel_launch(void* const* d_in, const int* in_sizes, int n_in,
                              void* d_out, int out_size, void* d_ws, size_t ws_size,
                              hipStream_t stream) {
    const f4* yp = (const f4*)d_in[0];
    const f4* yt = (const f4*)d_in[1];
    float* partial = (float*)d_ws;   // 1024 floats = 4 KB
    float* out = (float*)d_out;

    sdtw_stage1<<<B_ROWS * CHUNKS_PER_ROW, BLOCK, 0, stream>>>(yp, yt, partial);
    sdtw_stage2<<<1, 64, 0, stream>>>(partial, out);
}